// Round 2
// baseline (414.083 us; speedup 1.0000x reference)
//
#include <hip/hip_runtime.h>

#define N_NODES 100000
#define N_EDGES 1600000
#define NB ((N_NODES + 255) / 256)   // 391 blocks of 256

// ---------------- degree histogram (row = edge_index[0]) ----------------
__global__ __launch_bounds__(256) void hist_kernel(const int* __restrict__ row,
                                                   unsigned* __restrict__ deg, int E) {
    int i = blockIdx.x * 256 + threadIdx.x;
    if (i < E) atomicAdd(&deg[row[i]], 1u);
}

// ---------------- per-block sums of deg; also dinv = rsqrt(deg) ----------------
__global__ __launch_bounds__(256) void bsum_kernel(const unsigned* __restrict__ deg,
                                                   unsigned* __restrict__ bsum,
                                                   float* __restrict__ dinv, int n) {
    __shared__ unsigned lds[256];
    int t = threadIdx.x;
    int i = blockIdx.x * 256 + t;
    unsigned d = (i < n) ? deg[i] : 0u;
    if (i < n) dinv[i] = d > 0 ? rsqrtf((float)d) : 0.f;
    lds[t] = d;
    __syncthreads();
    for (int s = 128; s > 0; s >>= 1) {
        if (t < s) lds[t] += lds[t + s];
        __syncthreads();
    }
    if (t == 0) bsum[blockIdx.x] = lds[0];
}

// ---------------- exclusive scan of block sums (single block) ----------------
__global__ __launch_bounds__(512) void scanb_kernel(unsigned* __restrict__ bsum, int nb) {
    __shared__ unsigned lds[512];
    int t = threadIdx.x;
    unsigned v = (t < nb) ? bsum[t] : 0u;
    lds[t] = v;
    __syncthreads();
    for (int s = 1; s < 512; s <<= 1) {
        unsigned add = (t >= s) ? lds[t - s] : 0u;
        __syncthreads();
        lds[t] += add;
        __syncthreads();
    }
    if (t < nb) bsum[t] = lds[t] - v;   // exclusive prefix
}

// ---------------- per-block exclusive scan -> rowstart, cur ----------------
__global__ __launch_bounds__(256) void scan_kernel(const unsigned* __restrict__ deg,
                                                   const unsigned* __restrict__ bsum,
                                                   unsigned* __restrict__ rowstart,
                                                   unsigned* __restrict__ cur, int n) {
    __shared__ unsigned lds[256];
    int t = threadIdx.x;
    int i = blockIdx.x * 256 + t;
    unsigned v = (i < n) ? deg[i] : 0u;
    lds[t] = v;
    __syncthreads();
    for (int s = 1; s < 256; s <<= 1) {
        unsigned add = (t >= s) ? lds[t - s] : 0u;
        __syncthreads();
        lds[t] += add;
        __syncthreads();
    }
    if (i < n) {
        unsigned p = bsum[blockIdx.x] + lds[t] - v;
        rowstart[i] = p;
        cur[i] = p;
    }
}

// ---------------- scatter edges into CSR bins ----------------
__global__ __launch_bounds__(256) void scatter_kernel(const int* __restrict__ row,
                                                      const int* __restrict__ col,
                                                      unsigned* __restrict__ cur,
                                                      int* __restrict__ dstcol, int E) {
    int e = blockIdx.x * 256 + threadIdx.x;
    if (e < E) {
        unsigned p = atomicAdd(&cur[row[e]], 1u);
        dstcol[p] = col[e];
    }
}

// ---------------- layer1 projection: P0 = x@W1[0], P1 = x@W1[1] ----------------
__global__ __launch_bounds__(256) void proj1_kernel(const float* __restrict__ x,
                                                    const float* __restrict__ W1,
                                                    float* __restrict__ P0,
                                                    float* __restrict__ P1, int n) {
    __shared__ float lds[8 * 128];
    int base = blockIdx.x * 8;
    int t = threadIdx.x;
    for (int idx = t; idx < 8 * 128; idx += 256) {
        int nd = base + (idx >> 7);
        lds[idx] = (nd < n) ? x[(size_t)nd * 128 + (idx & 127)] : 0.f;
    }
    __syncthreads();
    int nl = t >> 5;     // node within block, 0..7
    int j  = t & 31;     // output index, 0..31
    int node = base + nl;
    if (node >= n) return;
    const float* w  = W1 + (j < 16 ? 0 : 2048) + (j & 15);  // W1 is (2,128,16)
    const float* xr = lds + nl * 128;
    float acc = 0.f;
#pragma unroll
    for (int k = 0; k < 128; ++k) acc += xr[k] * w[k * 16];
    if (j < 16) P0[(size_t)node * 16 + j]        = acc;
    else        P1[(size_t)node * 16 + (j - 16)] = acc;
}

// ---------------- agg1 + relu: h = relu(P0 + segsum(P1[c]*w) + b1) ----------------
// one wave per node; 4 edge-slots x 16 features per wave; no atomics.
__global__ __launch_bounds__(256) void agg1_kernel(const unsigned* __restrict__ rowstart,
                                                   const unsigned* __restrict__ deg,
                                                   const int* __restrict__ dstcol,
                                                   const float* __restrict__ dinv,
                                                   const float* __restrict__ P1,
                                                   const float* __restrict__ b1,
                                                   float* __restrict__ H,   // in: P0, out: h
                                                   int n) {
    int wave = threadIdx.x >> 6, lane = threadIdx.x & 63;
    int node = blockIdx.x * 4 + wave;
    if (node >= n) return;
    int f = lane & 15, slot = lane >> 4;
    unsigned start = rowstart[node], d = deg[node];
    float dr = dinv[node];
    float t = 0.f;
    for (unsigned j = slot; j < d; j += 4) {
        int c = dstcol[start + j];
        float w = -dr * dinv[c];
        t += P1[(size_t)c * 16 + f] * w;
    }
    t += __shfl_xor(t, 16);
    t += __shfl_xor(t, 32);
    if (slot == 0) {
        float v = H[(size_t)node * 16 + f] + t + b1[f];
        H[(size_t)node * 16 + f] = v > 0.f ? v : 0.f;
    }
}

// ---------------- agg2 + out-proj + log_softmax, fully fused ----------------
// one wave per node: t = segsum(h[c]*w); out = logsoftmax(h@W2[0] + t@W2[1] + b2)
__global__ __launch_bounds__(256) void agg2_out_kernel(const unsigned* __restrict__ rowstart,
                                                       const unsigned* __restrict__ deg,
                                                       const int* __restrict__ dstcol,
                                                       const float* __restrict__ dinv,
                                                       const float* __restrict__ H,
                                                       const float* __restrict__ W2,
                                                       const float* __restrict__ b2,
                                                       float* __restrict__ out, int n) {
    int wave = threadIdx.x >> 6, lane = threadIdx.x & 63;
    int node = blockIdx.x * 4 + wave;
    if (node >= n) return;
    int f = lane & 15, slot = lane >> 4;
    unsigned start = rowstart[node], d = deg[node];
    float dr = dinv[node];
    float t = 0.f;
    for (unsigned j = slot; j < d; j += 4) {
        int c = dstcol[start + j];
        float w = -dr * dinv[c];
        t += H[(size_t)c * 16 + f] * w;
    }
    t += __shfl_xor(t, 16);
    t += __shfl_xor(t, 32);
    // every lane now holds t for its f = lane&15; lane k (k<16) holds t[k]
    float o0 = b2[lane], o1 = b2[lane + 64];
    const float* h = H + (size_t)node * 16;
#pragma unroll
    for (int k = 0; k < 16; ++k) {
        float tk = __shfl(t, k);
        float hk = h[k];
        o0 += hk * W2[k * 128 + lane]      + tk * W2[2048 + k * 128 + lane];
        o1 += hk * W2[k * 128 + lane + 64] + tk * W2[2048 + k * 128 + lane + 64];
    }
    float m = fmaxf(o0, o1);
#pragma unroll
    for (int s = 1; s < 64; s <<= 1) m = fmaxf(m, __shfl_xor(m, s));
    float ssum = expf(o0 - m) + expf(o1 - m);
#pragma unroll
    for (int s = 1; s < 64; s <<= 1) ssum += __shfl_xor(ssum, s);
    float lse = m + logf(ssum);
    out[(size_t)node * 128 + lane]      = o0 - lse;
    out[(size_t)node * 128 + lane + 64] = o1 - lse;
}

extern "C" void kernel_launch(void* const* d_in, const int* in_sizes, int n_in,
                              void* d_out, int out_size, void* d_ws, size_t ws_size,
                              hipStream_t stream) {
    const float* x  = (const float*)d_in[0];
    const int*   ei = (const int*)d_in[1];
    const float* W1 = (const float*)d_in[2];
    const float* b1 = (const float*)d_in[3];
    const float* W2 = (const float*)d_in[4];
    const float* b2 = (const float*)d_in[5];
    float* out = (float*)d_out;

    const int n = N_NODES, E = N_EDGES;
    const int* row = ei;        // edge_index[0]
    const int* col = ei + E;    // edge_index[1]

    // workspace layout (all 4-byte elems), NPAD = 391*256 = 100096
    const size_t NPAD = 100096;
    unsigned* deg      = (unsigned*)d_ws;            // NPAD
    unsigned* rowstart = deg + NPAD;                 // NPAD
    unsigned* cur      = rowstart + NPAD;            // NPAD
    float*    dinv     = (float*)(cur + NPAD);       // NPAD
    unsigned* bsum     = (unsigned*)(dinv + NPAD);   // 512
    int*      dstcol   = (int*)(bsum + 512);         // E
    float*    P0       = (float*)(dstcol + E);       // NPAD*16
    float*    P1       = P0 + NPAD * 16;             // NPAD*16

    hipMemsetAsync(deg, 0, NPAD * sizeof(unsigned), stream);

    hist_kernel<<<(E + 255) / 256, 256, 0, stream>>>(row, deg, E);
    bsum_kernel<<<NB, 256, 0, stream>>>(deg, bsum, dinv, n);
    scanb_kernel<<<1, 512, 0, stream>>>(bsum, NB);
    scan_kernel<<<NB, 256, 0, stream>>>(deg, bsum, rowstart, cur, n);
    scatter_kernel<<<(E + 255) / 256, 256, 0, stream>>>(row, col, cur, dstcol, E);
    proj1_kernel<<<(n + 7) / 8, 256, 0, stream>>>(x, W1, P0, P1, n);
    agg1_kernel<<<(n + 3) / 4, 256, 0, stream>>>(rowstart, deg, dstcol, dinv, P1, b1, P0, n);
    agg2_out_kernel<<<(n + 3) / 4, 256, 0, stream>>>(rowstart, deg, dstcol, dinv, P0, W2, b2, out, n);
}